// Round 14
// baseline (209.550 us; speedup 1.0000x reference)
//
#include <hip/hip_runtime.h>
#include <math.h>

#define T_IN        480000
#define OUT_PER_ROW 432000
#define K_TOT       48000      // output 9-groups per row
#define BLK         256        // threads per block
#define GROUPS_PB   (2 * BLK)  // 512 k-groups per block (1 k-pair per thread)
#define OUT_LDS     (GROUPS_PB * 9)   // 4608 staged outputs per block

typedef float f32x4 __attribute__((ext_vector_type(4)));  // native vector: OK for nontemporal builtin

struct ResampleW { float w[9][14]; };

__global__ __launch_bounds__(BLK)
void SpeedPerturb_resample_kernel(const float* __restrict__ in,
                                  float* __restrict__ out,
                                  ResampleW args)
{
    __shared__ float lout[OUT_LDS];
    const int row = blockIdx.y;
    const int k0  = blockIdx.x * GROUPS_PB;
    const int t   = threadIdx.x;
    const int kp  = (k0 >> 1) + t;                // this thread's k-pair
    const float* rin = in + (size_t)row * T_IN;

    // Window for pair kp: input[20*kp-6 .. 20*kp+26]; 16B-aligned base 20*kp-8.
    const int al = 20 * kp - 8;
    float v[36];
    const bool interior = (blockIdx.x > 0) && (blockIdx.x < gridDim.x - 1);
    if (interior) {
        // Issue ALL 9 dwordx4 loads before any consumer (forced MLP).
        f32x4 r0 = *reinterpret_cast<const f32x4*>(rin + al);
        f32x4 r1 = *reinterpret_cast<const f32x4*>(rin + al + 4);
        f32x4 r2 = *reinterpret_cast<const f32x4*>(rin + al + 8);
        f32x4 r3 = *reinterpret_cast<const f32x4*>(rin + al + 12);
        f32x4 r4 = *reinterpret_cast<const f32x4*>(rin + al + 16);
        f32x4 r5 = *reinterpret_cast<const f32x4*>(rin + al + 20);
        f32x4 r6 = *reinterpret_cast<const f32x4*>(rin + al + 24);
        f32x4 r7 = *reinterpret_cast<const f32x4*>(rin + al + 28);
        f32x4 r8 = *reinterpret_cast<const f32x4*>(rin + al + 32);
        __builtin_amdgcn_sched_barrier(0);
        #pragma unroll
        for (int c = 0; c < 4; ++c) {
            v[c]      = r0[c]; v[4 + c]  = r1[c]; v[8 + c]  = r2[c];
            v[12 + c] = r3[c]; v[16 + c] = r4[c]; v[20 + c] = r5[c];
            v[24 + c] = r6[c]; v[28 + c] = r7[c]; v[32 + c] = r8[c];
        }
    } else {
        #pragma unroll
        for (int m = 0; m < 36; ++m) {
            const int idx = al + m;
            v[m] = (idx >= 0 && idx < T_IN) ? rin[idx] : 0.f;
        }
    }

    // RB[i] = fi[i] + 6, fi = ceil(i*10/9 - 6.7340067) = {-6..-1,0,2,3}
    constexpr int RB[9] = {0, 1, 2, 3, 4, 5, 6, 8, 9};

    #pragma unroll
    for (int g = 0; g < 2; ++g) {
        const int k = k0 + 2 * t + g;
        if (k < K_TOT) {
            #pragma unroll
            for (int i = 0; i < 9; ++i) {
                float s = 0.f;
                #pragma unroll
                for (int j = 0; j < 14; ++j)
                    s = fmaf(args.w[i][j], v[2 + 10 * g + RB[i] + j], s);
                lout[18 * t + 9 * g + i] = s;
            }
        }
    }
    __syncthreads();

    // Coalesced NON-TEMPORAL float4 store of the block's contiguous output:
    // bypass L2 allocation so the write stream doesn't evict the input stream.
    const int gcount = min(GROUPS_PB, K_TOT - k0);     // 512 or 384 (last block)
    const int nq = (gcount * 9) >> 2;                  // both divisible by 4
    float* obase = out + (size_t)row * OUT_PER_ROW + (size_t)k0 * 9;
    for (int q = t; q < nq; q += BLK) {
        const f32x4 val = *reinterpret_cast<const f32x4*>(&lout[4 * q]);
        __builtin_nontemporal_store(val, reinterpret_cast<f32x4*>(obase + 4 * q));
    }
}

extern "C" void kernel_launch(void* const* d_in, const int* in_sizes, int n_in,
                              void* d_out, int out_size, void* d_ws, size_t ws_size,
                              hipStream_t stream) {
    const float* in  = (const float*)d_in[0];
    float*       out = (float*)d_out;
    const int B = out_size / OUT_PER_ROW;

    // Kaldi LinearResample weights, float64 math mirroring the reference.
    ResampleW args;
    const double orig = 16000.0;
    const double lowpass_cutoff = 0.99 * 0.5 * 14400.0;     // min_freq = 14400
    const double window_width = 6.0 / (2.0 * lowpass_cutoff);
    const double PI = 3.14159265358979323846;
    for (int i = 0; i < 9; ++i) {
        const double output_t = (double)i / 14400.0;
        const double min_input_index = ceil((output_t - window_width) * orig);
        for (int j = 0; j < 14; ++j) {
            const double delta_t = (min_input_index + j) / orig - output_t;
            double w = 0.0;
            if (fabs(delta_t) < window_width) {
                w = 0.5 * (1.0 + cos(2.0 * PI * lowpass_cutoff / 6.0 * delta_t));
                if (delta_t != 0.0)
                    w *= sin(2.0 * PI * lowpass_cutoff * delta_t) / (PI * delta_t);
                else
                    w *= 2.0 * lowpass_cutoff;
                w /= orig;
            }
            args.w[i][j] = (float)w;
        }
    }

    dim3 grid((K_TOT + GROUPS_PB - 1) / GROUPS_PB, B);   // 94 x 64
    SpeedPerturb_resample_kernel<<<grid, dim3(BLK), 0, stream>>>(in, out, args);
}